// Round 3
// baseline (209.512 us; speedup 1.0000x reference)
//
#include <hip/hip_runtime.h>
#include <hip/hip_bf16.h>

// out[512, 65536] = inputs[512,256] @ features[65536,256]^T  (fp32 in/out)
//
// v4: barrier-free main loop.
//   - B panel [128][256] fp32 -> bf16 staged to LDS ONCE per block (64 KB,
//     XOR-swizzled, conflict-free ds_read_b128). One barrier, then read-only.
//   - A pre-converted to bf16 ws (row-major). MFMA A-fragments loaded DIRECTLY
//     from global (L2-resident 256 KB) -> no As LDS, no DMA, no per-step sync.
//   - 4 m-passes; waves free-run; compiler pipelines L2 loads under MFMA.
//   - Traffic: B 64 MB (once) + C 128 MB + A ~0  ->  ~28 us BW floor.

#define M_DIM 512
#define N_DIM 65536
#define K_DIM 256
#define BN 128
#define MP 128          // rows per m-pass

typedef __bf16 bf16x8 __attribute__((ext_vector_type(8)));
typedef float f32x4 __attribute__((ext_vector_type(4)));

// ---- kernel 1: inputs [512][256] fp32 -> bf16 ws, row-major ----
__global__ __launch_bounds__(256) void cvt_inputs(const float* __restrict__ A,
                                                  __bf16* __restrict__ Aw) {
    const int t = blockIdx.x * 256 + threadIdx.x;   // 16384 threads x 8 elems
    const float* src = A + (size_t)t * 8;
    f32x4 v0 = *(const f32x4*)src;
    f32x4 v1 = *(const f32x4*)(src + 4);
    bf16x8 h;
    h[0] = (__bf16)v0[0]; h[1] = (__bf16)v0[1];
    h[2] = (__bf16)v0[2]; h[3] = (__bf16)v0[3];
    h[4] = (__bf16)v1[0]; h[5] = (__bf16)v1[1];
    h[6] = (__bf16)v1[2]; h[7] = (__bf16)v1[3];
    *(bf16x8*)(Aw + (size_t)t * 8) = h;
}

__global__ __launch_bounds__(256, 2) void hm_gemm_bt(
    const __bf16* __restrict__ Aw,  // [512][256] bf16 ws (L2-resident)
    const float*  __restrict__ B,   // features [65536][256] fp32
    float* __restrict__ C)          // out [512][65536] fp32
{
    __shared__ __align__(16) __bf16 Bs[BN * K_DIM];  // 64 KB, full-K B panel

    const int tid  = threadIdx.x;
    const int lane = tid & 63;
    const int wave = tid >> 6;            // 4 waves, 2x2 grid of 64x64 subtiles
    const int wm   = (wave >> 1) * 64;
    const int wn   = (wave & 1) * 64;

    const int n0 = blockIdx.x * BN;       // grid = 512, one n-panel per block

    const int lrow = lane & 15;
    const int lk   = (lane >> 4) * 8;
    const int lx   = lrow & 7;            // XOR key for swizzled Bs reads

    // ---- stage full B panel once: 128 rows x 256 k, fp32 -> bf16, swizzled
    #pragma unroll 4
    for (int it = 0; it < 16; ++it) {
        const int c   = it * 256 + tid;   // 0..4095 bf16x8 slots
        const int row = c >> 5;
        const int s   = c & 31;
        const float* src = B + (size_t)(n0 + row) * K_DIM + s * 8;
        f32x4 v0 = *(const f32x4*)(src);
        f32x4 v1 = *(const f32x4*)(src + 4);
        bf16x8 h;
        h[0] = (__bf16)v0[0]; h[1] = (__bf16)v0[1];
        h[2] = (__bf16)v0[2]; h[3] = (__bf16)v0[3];
        h[4] = (__bf16)v1[0]; h[5] = (__bf16)v1[1];
        h[6] = (__bf16)v1[2]; h[7] = (__bf16)v1[3];
        const int sst = s ^ (row & 7);
        *(bf16x8*)&Bs[row * K_DIM + sst * 8] = h;
    }
    __syncthreads();                      // Bs read-only from here: no more barriers

    for (int mp = 0; mp < M_DIM / MP; ++mp) {
        f32x4 acc[4][4];
        #pragma unroll
        for (int i = 0; i < 4; ++i)
            #pragma unroll
            for (int j = 0; j < 4; ++j)
                acc[i][j] = f32x4{0.f, 0.f, 0.f, 0.f};

        const __bf16* Ab = Aw + (size_t)(mp * MP + wm + lrow) * K_DIM + lk;

        #pragma unroll 4
        for (int k = 0; k < K_DIM; k += 32) {
            bf16x8 af[4], bfr[4];
            // A fragments straight from global (L2): rows wm+i*16+lrow, 16 B each
            #pragma unroll
            for (int i = 0; i < 4; ++i)
                af[i] = *(const bf16x8*)(Ab + (size_t)(i * 16) * K_DIM + k);
            // B fragments from swizzled LDS (conflict-free)
            #pragma unroll
            for (int j = 0; j < 4; ++j) {
                const int row = wn + j * 16 + lrow;
                const int pos = (((k + lk) >> 3) ^ lx);
                bfr[j] = *(const bf16x8*)&Bs[row * K_DIM + pos * 8];
            }
            #pragma unroll
            for (int i = 0; i < 4; ++i)
                #pragma unroll
                for (int j = 0; j < 4; ++j)
                    acc[i][j] = __builtin_amdgcn_mfma_f32_16x16x32_bf16(
                        bfr[j], af[i], acc[i][j], 0, 0, 0);  // swapped: D.row -> n
        }

        // ---- epilogue: lane holds C[m = ..+lane&15][n = ..+(lane>>4)*4+0..3]
        const int lm = lane & 15;
        const int ln = (lane >> 4) * 4;
        #pragma unroll
        for (int i = 0; i < 4; ++i) {
            const size_t rowbase = (size_t)(mp * MP + wm + i * 16 + lm) * N_DIM;
            #pragma unroll
            for (int j = 0; j < 4; ++j) {
                float* dst = C + rowbase + (n0 + wn + j * 16 + ln);
                *(f32x4*)dst = acc[i][j];
            }
        }
    }
}

extern "C" void kernel_launch(void* const* d_in, const int* in_sizes, int n_in,
                              void* d_out, int out_size, void* d_ws, size_t ws_size,
                              hipStream_t stream) {
    // setup_inputs order: inputs, indexes, features, mIoU, IoU
    const float* inputs   = (const float*)d_in[0];
    const float* features = (const float*)d_in[2];
    float* out = (float*)d_out;
    __bf16* Aw = (__bf16*)d_ws;          // 256 KB of workspace

    hipLaunchKernelGGL(cvt_inputs, dim3(M_DIM * K_DIM / (256 * 8)), dim3(256),
                       0, stream, inputs, Aw);

    hipLaunchKernelGGL(hm_gemm_bt, dim3(N_DIM / BN), dim3(256), 0, stream,
                       Aw, features, out);
}